// Round 2
// baseline (1090.652 us; speedup 1.0000x reference)
//
#include <hip/hip_runtime.h>

#define NPTS 131072
#define K 27
#define CIN 64
#define COUT 128
#define PTS 8   // points per conv block

constexpr float BN_EPS = 1e-5f;
constexpr float NEG_SLOPE = 0.01f;

// ---------------------------------------------------------------------------
// Kernel 1: sparse gather-conv.  Block = 128 threads (one per output channel),
// processes PTS points.  Gathered+masked feats rows staged in LDS as
// g[ci][p] so the compute loop's per-ci read of 8 consecutive floats is a
// wave-uniform broadcast (conflict-free).  8 FMAs amortize each W load; the
// 32 KB W k-slice is reused by every block -> L1/L2 resident.
// ---------------------------------------------------------------------------
__global__ __launch_bounds__(128) void conv_kernel(
    const float* __restrict__ feats,
    const int* __restrict__ nidx,
    const int* __restrict__ nmask,       // harness pushes jnp bool as int32
    const float* __restrict__ W,
    float* __restrict__ y)
{
    __shared__ float g[CIN][PTS];
    const int c = threadIdx.x;            // output channel 0..127
    const int base = blockIdx.x * PTS;    // first point of this block

    float acc[PTS];
#pragma unroll
    for (int p = 0; p < PTS; ++p) acc[p] = 0.f;

    for (int k = 0; k < K; ++k) {
        __syncthreads();
        // stage PTS*64 = 512 floats with 128 threads -> 4 elems/thread.
#pragma unroll
        for (int e = 0; e < (PTS * CIN) / 128; ++e) {
            int li = c + 128 * e;
            int p  = li >> 6;
            int ci = li & 63;
            int i  = base + p;
            int id = nidx[i * K + k];
            float v = nmask[i * K + k] ? feats[id * CIN + ci] : 0.f;
            g[ci][p] = v;
        }
        __syncthreads();
        const float* Wk = W + k * CIN * COUT;
#pragma unroll 4
        for (int ci = 0; ci < CIN; ++ci) {
            float w = Wk[ci * COUT + c];   // coalesced across lanes
#pragma unroll
            for (int p = 0; p < PTS; ++p)
                acc[p] += g[ci][p] * w;    // g[ci][*]: broadcast read
        }
    }
#pragma unroll
    for (int p = 0; p < PTS; ++p)
        y[(base + p) * COUT + c] = acc[p];
}

// ---------------------------------------------------------------------------
// Kernel 2: per-channel sum / sumsq.  Block = 128 threads (one per channel),
// grid-stride over rows; one double atomicAdd per (block, channel, stat).
// ---------------------------------------------------------------------------
__global__ __launch_bounds__(128) void stats_kernel(
    const float* __restrict__ y, double* __restrict__ stats)
{
    const int c = threadIdx.x;
    float s = 0.f, s2 = 0.f;
    for (int i = blockIdx.x; i < NPTS; i += gridDim.x) {
        float v = y[i * COUT + c];
        s += v;
        s2 += v * v;
    }
    atomicAdd(&stats[c], (double)s);
    atomicAdd(&stats[COUT + c], (double)s2);
}

// ---------------------------------------------------------------------------
// Kernel 3: BN normalize + LeakyReLU, in place on y (= d_out).
// ---------------------------------------------------------------------------
__global__ __launch_bounds__(256) void bn_kernel(
    float* __restrict__ y, const double* __restrict__ stats,
    const float* __restrict__ gamma, const float* __restrict__ beta)
{
    const float invN = 1.0f / (float)NPTS;
    for (int idx = blockIdx.x * blockDim.x + threadIdx.x;
         idx < NPTS * COUT; idx += gridDim.x * blockDim.x) {
        int c = idx & (COUT - 1);
        float mean = (float)(stats[c] * invN);
        float var  = (float)(stats[COUT + c] * invN) - mean * mean;
        float v = (y[idx] - mean) * rsqrtf(var + BN_EPS) * gamma[c] + beta[c];
        y[idx] = v > 0.f ? v : NEG_SLOPE * v;
    }
}

extern "C" void kernel_launch(void* const* d_in, const int* in_sizes, int n_in,
                              void* d_out, int out_size, void* d_ws, size_t ws_size,
                              hipStream_t stream)
{
    const float* feats = (const float*)d_in[0];
    const int*   nidx  = (const int*)d_in[1];
    const int*   nmask = (const int*)d_in[2];
    const float* W     = (const float*)d_in[3];
    const float* gamma = (const float*)d_in[4];
    const float* beta  = (const float*)d_in[5];

    float*  y     = (float*)d_out;           // conv output lives in d_out
    double* stats = (double*)d_ws;           // 256 doubles

    hipMemsetAsync(d_ws, 0, 2 * COUT * sizeof(double), stream);

    conv_kernel<<<NPTS / PTS, 128, 0, stream>>>(feats, nidx, nmask, W, y);
    stats_kernel<<<1024, 128, 0, stream>>>(y, stats);
    bn_kernel<<<2048, 256, 0, stream>>>(y, stats, gamma, beta);
}

// Round 3
// 231.981 us; speedup vs baseline: 4.7015x; 4.7015x over previous
//
#include <hip/hip_runtime.h>
#include <hip/hip_bf16.h>

#define NPTS 131072
#define K 27
#define CIN 64
#define COUT 128
#define BM 64                 // rows per conv block

constexpr float BN_EPS = 1e-5f;
constexpr float NEG_SLOPE = 0.01f;

typedef __attribute__((ext_vector_type(8))) short short8;
typedef __attribute__((ext_vector_type(4))) float f32x4;

__device__ inline unsigned int pk_bf16(float a, float b) {
    __hip_bfloat16 ha = __float2bfloat16(a), hb = __float2bfloat16(b);
    unsigned short ua = *reinterpret_cast<unsigned short*>(&ha);
    unsigned short ub = *reinterpret_cast<unsigned short*>(&hb);
    return (unsigned int)ua | ((unsigned int)ub << 16);
}

// ---------------------------------------------------------------------------
// Kernel 0: W [27][64][128] f32  ->  Wt [27][128][64] bf16 (in d_ws)
// ---------------------------------------------------------------------------
__global__ __launch_bounds__(256) void prep_kernel(
    const float* __restrict__ W, unsigned short* __restrict__ Wt)
{
    int o = blockIdx.x * 256 + threadIdx.x;           // 27*128*64 = 221184
    if (o >= K * COUT * CIN) return;
    int k  = o / (COUT * CIN);
    int r  = o % (COUT * CIN);
    int co = r / CIN;
    int ci = r % CIN;
    __hip_bfloat16 h = __float2bfloat16(W[(k * CIN + ci) * COUT + co]);
    Wt[o] = *reinterpret_cast<unsigned short*>(&h);
}

// ---------------------------------------------------------------------------
// Kernel 1: MFMA gather-conv.  256 threads = 4 waves (2x2), 64x128 out tile.
// A: gathered feats rows -> bf16 -> LDS [64][64] (XOR-swizzled, T2)
// B: Wt k-slice          -> LDS [128][64]  (XOR-swizzled)
// 2-barrier loop over 27 k-offsets, 2 MFMA K-steps (of 32) each.
// ---------------------------------------------------------------------------
__global__ __launch_bounds__(256) void conv_kernel(
    const float* __restrict__ feats,
    const int* __restrict__ nidx,
    const int* __restrict__ nmask,
    const unsigned short* __restrict__ Wt,
    float* __restrict__ y)
{
    __shared__ unsigned char Alds[BM * CIN * 2];      // 8 KB  [row][ci] bf16
    __shared__ unsigned char Blds[COUT * CIN * 2];    // 16 KB [col][ci] bf16

    const int tid  = threadIdx.x;
    const int l    = tid & 63;
    const int wid  = tid >> 6;
    const int wr   = wid >> 1;        // wave row 0..1  (32 rows each)
    const int wc   = wid & 1;         // wave col 0..1  (64 cols each)
    const int base = blockIdx.x * BM;

    // A-staging role: 4 threads per row, 16 floats each
    const int arow = tid >> 2;
    const int aq   = tid & 3;
    // B-staging role: 2 threads per col, 32 bf16 each
    const int bcol = tid >> 1;
    const int bh   = tid & 1;

    f32x4 acc[2][4];
#pragma unroll
    for (int m = 0; m < 2; ++m)
#pragma unroll
        for (int n = 0; n < 4; ++n) acc[m][n] = (f32x4)0.f;

    for (int k = 0; k < K; ++k) {
        __syncthreads();              // previous MFMA reads done

        // ---- stage A (gather + mask + cvt) ----
        {
            int i  = base + arow;
            int id = nidx[i * K + k];
            unsigned int w0[4], w1[4];
            if (nmask[i * K + k]) {
                const float4* src = (const float4*)(feats + (size_t)id * CIN + aq * 16);
                float4 v0 = src[0], v1 = src[1], v2 = src[2], v3 = src[3];
                w0[0] = pk_bf16(v0.x, v0.y); w0[1] = pk_bf16(v0.z, v0.w);
                w0[2] = pk_bf16(v1.x, v1.y); w0[3] = pk_bf16(v1.z, v1.w);
                w1[0] = pk_bf16(v2.x, v2.y); w1[1] = pk_bf16(v2.z, v2.w);
                w1[2] = pk_bf16(v3.x, v3.y); w1[3] = pk_bf16(v3.z, v3.w);
            } else {
#pragma unroll
                for (int j = 0; j < 4; ++j) { w0[j] = 0u; w1[j] = 0u; }
            }
            int swz = (arow & 7) << 4;
            unsigned char* ap = Alds + arow * 128;
            *(uint4*)(ap + ((aq * 32 +  0) ^ swz)) = make_uint4(w0[0], w0[1], w0[2], w0[3]);
            *(uint4*)(ap + ((aq * 32 + 16) ^ swz)) = make_uint4(w1[0], w1[1], w1[2], w1[3]);
        }
        // ---- stage B (copy Wt k-slice) ----
        {
            const uint4* src = (const uint4*)(Wt + ((size_t)k * COUT + bcol) * CIN + bh * 32);
            int swz = (bcol & 7) << 4;
            unsigned char* bp = Blds + bcol * 128;
#pragma unroll
            for (int c = 0; c < 4; ++c)
                *(uint4*)(bp + ((bh * 64 + c * 16) ^ swz)) = src[c];
        }
        __syncthreads();

        // ---- MFMA: 2 K-steps of 32 ----
#pragma unroll
        for (int ks = 0; ks < 2; ++ks) {
            const int kbyte = ks * 64 + (l >> 4) * 16;
            short8 a[2], b[4];
#pragma unroll
            for (int m = 0; m < 2; ++m) {
                int row = wr * 32 + m * 16 + (l & 15);
                a[m] = *(const short8*)(Alds + row * 128 + (kbyte ^ ((row & 7) << 4)));
            }
#pragma unroll
            for (int n = 0; n < 4; ++n) {
                int col = wc * 64 + n * 16 + (l & 15);
                b[n] = *(const short8*)(Blds + col * 128 + (kbyte ^ ((col & 7) << 4)));
            }
#pragma unroll
            for (int m = 0; m < 2; ++m)
#pragma unroll
                for (int n = 0; n < 4; ++n)
                    acc[m][n] = __builtin_amdgcn_mfma_f32_16x16x32_bf16(
                        a[m], b[n], acc[m][n], 0, 0, 0);
        }
    }

    // ---- epilogue: C/D layout col=l&15, row=(l>>4)*4+r  (m89) ----
#pragma unroll
    for (int m = 0; m < 2; ++m)
#pragma unroll
        for (int n = 0; n < 4; ++n) {
            int gcol = wc * 64 + n * 16 + (l & 15);
#pragma unroll
            for (int r = 0; r < 4; ++r) {
                int grow = base + wr * 32 + m * 16 + (l >> 4) * 4 + r;
                y[(size_t)grow * COUT + gcol] = acc[m][n][r];
            }
        }
}

// ---------------------------------------------------------------------------
// Kernel 2: per-channel sum / sumsq (double atomics into d_ws)
// ---------------------------------------------------------------------------
__global__ __launch_bounds__(128) void stats_kernel(
    const float* __restrict__ y, double* __restrict__ stats)
{
    const int c = threadIdx.x;
    float s = 0.f, s2 = 0.f;
    for (int i = blockIdx.x; i < NPTS; i += gridDim.x) {
        float v = y[i * COUT + c];
        s += v;
        s2 += v * v;
    }
    atomicAdd(&stats[c], (double)s);
    atomicAdd(&stats[COUT + c], (double)s2);
}

// ---------------------------------------------------------------------------
// Kernel 3: BN normalize + LeakyReLU, in place
// ---------------------------------------------------------------------------
__global__ __launch_bounds__(256) void bn_kernel(
    float* __restrict__ y, const double* __restrict__ stats,
    const float* __restrict__ gamma, const float* __restrict__ beta)
{
    const float invN = 1.0f / (float)NPTS;
    for (int idx = blockIdx.x * blockDim.x + threadIdx.x;
         idx < NPTS * COUT; idx += gridDim.x * blockDim.x) {
        int c = idx & (COUT - 1);
        float mean = (float)(stats[c] * invN);
        float var  = (float)(stats[COUT + c] * invN) - mean * mean;
        float v = (y[idx] - mean) * rsqrtf(var + BN_EPS) * gamma[c] + beta[c];
        y[idx] = v > 0.f ? v : NEG_SLOPE * v;
    }
}

extern "C" void kernel_launch(void* const* d_in, const int* in_sizes, int n_in,
                              void* d_out, int out_size, void* d_ws, size_t ws_size,
                              hipStream_t stream)
{
    const float* feats = (const float*)d_in[0];
    const int*   nidx  = (const int*)d_in[1];
    const int*   nmask = (const int*)d_in[2];
    const float* W     = (const float*)d_in[3];
    const float* gamma = (const float*)d_in[4];
    const float* beta  = (const float*)d_in[5];

    float*          y     = (float*)d_out;
    double*         stats = (double*)d_ws;                         // 2 KB
    unsigned short* Wt    = (unsigned short*)((char*)d_ws + 4096); // 442 KB

    hipMemsetAsync(d_ws, 0, 2 * COUT * sizeof(double), stream);

    prep_kernel<<<(K * COUT * CIN + 255) / 256, 256, 0, stream>>>(W, Wt);
    conv_kernel<<<NPTS / BM, 256, 0, stream>>>(feats, nidx, nmask, Wt, y);
    stats_kernel<<<1024, 128, 0, stream>>>(y, stats);
    bn_kernel<<<2048, 256, 0, stream>>>(y, stats, gamma, beta);
}

// Round 4
// 173.317 us; speedup vs baseline: 6.2928x; 1.3385x over previous
//
#include <hip/hip_runtime.h>
#include <hip/hip_bf16.h>

#define NPTS 131072
#define K 27
#define CIN 64
#define COUT 128
#define BM 64                 // rows per conv block

constexpr float BN_EPS = 1e-5f;
constexpr float NEG_SLOPE = 0.01f;

typedef __attribute__((ext_vector_type(8))) short short8;
typedef __attribute__((ext_vector_type(4))) float f32x4;

__device__ inline unsigned int pk_bf16(float a, float b) {
    __hip_bfloat16 ha = __float2bfloat16(a), hb = __float2bfloat16(b);
    unsigned short ua = *reinterpret_cast<unsigned short*>(&ha);
    unsigned short ub = *reinterpret_cast<unsigned short*>(&hb);
    return (unsigned int)ua | ((unsigned int)ub << 16);
}

// ---------------------------------------------------------------------------
// prep_w: W [27][64][128] f32 -> Wt [27][128][64] bf16
// ---------------------------------------------------------------------------
__global__ __launch_bounds__(256) void prep_w(
    const float* __restrict__ W, unsigned short* __restrict__ Wt)
{
    int o = blockIdx.x * 256 + threadIdx.x;           // 27*128*64 = 221184
    if (o >= K * COUT * CIN) return;
    int k  = o / (COUT * CIN);
    int r  = o % (COUT * CIN);
    int co = r / CIN;
    int ci = r % CIN;
    __hip_bfloat16 h = __float2bfloat16(W[(k * CIN + ci) * COUT + co]);
    Wt[o] = *reinterpret_cast<unsigned short*>(&h);
}

// ---------------------------------------------------------------------------
// prep_f: feats [N][64] f32 -> bf16 (halves gather traffic in conv)
// ---------------------------------------------------------------------------
__global__ __launch_bounds__(256) void prep_f(
    const float* __restrict__ feats, unsigned short* __restrict__ featsb)
{
    size_t t = (size_t)blockIdx.x * 256 + threadIdx.x;   // 1,048,576 threads
    const float4* src = (const float4*)(feats) + t * 2;
    float4 v0 = src[0], v1 = src[1];
    uint4 o;
    o.x = pk_bf16(v0.x, v0.y); o.y = pk_bf16(v0.z, v0.w);
    o.z = pk_bf16(v1.x, v1.y); o.w = pk_bf16(v1.z, v1.w);
    ((uint4*)featsb)[t] = o;
}

// ---------------------------------------------------------------------------
// conv: MFMA gather-conv, 256 thr = 4 waves (2x2), 64x128 tile, fused stats.
// ---------------------------------------------------------------------------
template<bool BF16F>
__global__ __launch_bounds__(256) void conv_kernel(
    const float* __restrict__ feats,
    const unsigned short* __restrict__ featsb,
    const int* __restrict__ nidx,
    const int* __restrict__ nmask,
    const unsigned short* __restrict__ Wt,
    float* __restrict__ y,
    float* __restrict__ accum)          // [256]: sums then sumsqs
{
    __shared__ unsigned char Alds[BM * CIN * 2];      // 8 KB
    __shared__ unsigned char Blds[COUT * CIN * 2];    // 16 KB
    __shared__ float statbuf[2][2][128];              // 2 KB  [s/s2][wr][c]

    const int tid  = threadIdx.x;
    const int l    = tid & 63;
    const int wid  = tid >> 6;
    const int wr   = wid >> 1;
    const int wc   = wid & 1;
    const int base = blockIdx.x * BM;

    const int arow = tid >> 2;        // 4 threads/row
    const int aq   = tid & 3;
    const int bcol = tid >> 1;        // 2 threads/col
    const int bh   = tid & 1;

    f32x4 acc[2][4];
#pragma unroll
    for (int m = 0; m < 2; ++m)
#pragma unroll
        for (int n = 0; n < 4; ++n) acc[m][n] = (f32x4)0.f;

    for (int k = 0; k < K; ++k) {
        __syncthreads();
        // ---- stage A (gather, mask, -> swizzled LDS) ----
        {
            int i  = base + arow;
            int id = nidx[i * K + k];
            uint4 v0 = make_uint4(0,0,0,0), v1 = make_uint4(0,0,0,0);
            if (nmask[i * K + k]) {
                if constexpr (BF16F) {
                    const uint4* src = (const uint4*)(featsb + (size_t)id * CIN + aq * 16);
                    v0 = src[0]; v1 = src[1];
                } else {
                    const float4* src = (const float4*)(feats + (size_t)id * CIN + aq * 16);
                    float4 a0 = src[0], a1 = src[1], a2 = src[2], a3 = src[3];
                    v0 = make_uint4(pk_bf16(a0.x,a0.y), pk_bf16(a0.z,a0.w),
                                    pk_bf16(a1.x,a1.y), pk_bf16(a1.z,a1.w));
                    v1 = make_uint4(pk_bf16(a2.x,a2.y), pk_bf16(a2.z,a2.w),
                                    pk_bf16(a3.x,a3.y), pk_bf16(a3.z,a3.w));
                }
            }
            int swz = (arow & 7) << 4;
            unsigned char* ap = Alds + arow * 128;
            *(uint4*)(ap + ((aq * 32 +  0) ^ swz)) = v0;
            *(uint4*)(ap + ((aq * 32 + 16) ^ swz)) = v1;
        }
        // ---- stage B (Wt k-slice -> swizzled LDS) ----
        {
            const uint4* src = (const uint4*)(Wt + ((size_t)k * COUT + bcol) * CIN + bh * 32);
            int swz = (bcol & 7) << 4;
            unsigned char* bp = Blds + bcol * 128;
#pragma unroll
            for (int c = 0; c < 4; ++c)
                *(uint4*)(bp + ((bh * 64 + c * 16) ^ swz)) = src[c];
        }
        __syncthreads();

        // ---- 2 MFMA K-steps of 32 ----
#pragma unroll
        for (int ks = 0; ks < 2; ++ks) {
            const int kbyte = ks * 64 + (l >> 4) * 16;
            short8 a[2], b[4];
#pragma unroll
            for (int m = 0; m < 2; ++m) {
                int row = wr * 32 + m * 16 + (l & 15);
                a[m] = *(const short8*)(Alds + row * 128 + (kbyte ^ ((row & 7) << 4)));
            }
#pragma unroll
            for (int n = 0; n < 4; ++n) {
                int col = wc * 64 + n * 16 + (l & 15);
                b[n] = *(const short8*)(Blds + col * 128 + (kbyte ^ ((col & 7) << 4)));
            }
#pragma unroll
            for (int m = 0; m < 2; ++m)
#pragma unroll
                for (int n = 0; n < 4; ++n)
                    acc[m][n] = __builtin_amdgcn_mfma_f32_16x16x32_bf16(
                        a[m], b[n], acc[m][n], 0, 0, 0);
        }
    }

    // ---- y write: C/D layout col=l&15, row=(l>>4)*4+r ----
#pragma unroll
    for (int m = 0; m < 2; ++m)
#pragma unroll
        for (int n = 0; n < 4; ++n) {
            int gcol = wc * 64 + n * 16 + (l & 15);
#pragma unroll
            for (int r = 0; r < 4; ++r) {
                int grow = base + wr * 32 + m * 16 + (l >> 4) * 4 + r;
                y[(size_t)grow * COUT + gcol] = acc[m][n][r];
            }
        }

    // ---- fused per-block BN stats -> one f32 atomic per channel ----
#pragma unroll
    for (int n = 0; n < 4; ++n) {
        float s = 0.f, s2 = 0.f;
#pragma unroll
        for (int m = 0; m < 2; ++m)
#pragma unroll
            for (int r = 0; r < 4; ++r) { float v = acc[m][n][r]; s += v; s2 += v * v; }
        s  += __shfl_xor(s, 16);  s  += __shfl_xor(s, 32);
        s2 += __shfl_xor(s2, 16); s2 += __shfl_xor(s2, 32);
        if (l < 16) {
            int c = wc * 64 + n * 16 + l;
            statbuf[0][wr][c] = s;
            statbuf[1][wr][c] = s2;
        }
    }
    __syncthreads();
    if (tid < 128) {
        atomicAdd(&accum[tid],       statbuf[0][0][tid] + statbuf[0][1][tid]);
        atomicAdd(&accum[128 + tid], statbuf[1][0][tid] + statbuf[1][1][tid]);
    }
}

// ---------------------------------------------------------------------------
// finalize: fold mean/var/gamma/beta into per-channel scale+bias
// ---------------------------------------------------------------------------
__global__ void finalize_kernel(const float* __restrict__ accum,
                                const float* __restrict__ gamma,
                                const float* __restrict__ beta,
                                float* __restrict__ sb)
{
    int c = threadIdx.x;                      // 128 threads
    float invN  = 1.0f / (float)NPTS;
    float mean  = accum[c] * invN;
    float var   = accum[128 + c] * invN - mean * mean;
    float scale = gamma[c] * rsqrtf(var + BN_EPS);
    sb[c]       = scale;
    sb[128 + c] = beta[c] - mean * scale;
}

// ---------------------------------------------------------------------------
// bn: y = leaky(y*scale+bias), float4-vectorized, scale/bias in registers
// ---------------------------------------------------------------------------
__global__ __launch_bounds__(256) void bn_kernel(
    float* __restrict__ y, const float* __restrict__ sb)
{
    size_t start = (size_t)blockIdx.x * blockDim.x + threadIdx.x;
    // channel group is invariant under grid-stride (stride % 32 == 0)
    int c0 = (int)((start * 4) & (COUT - 1));
    float sc[4], bi[4];
#pragma unroll
    for (int j = 0; j < 4; ++j) { sc[j] = sb[c0 + j]; bi[j] = sb[COUT + c0 + j]; }

    const size_t total = (size_t)NPTS * COUT / 4;
    const size_t step  = (size_t)gridDim.x * blockDim.x;
    for (size_t idx = start; idx < total; idx += step) {
        float4 v = ((const float4*)y)[idx];
        v.x = v.x * sc[0] + bi[0]; v.x = v.x > 0.f ? v.x : NEG_SLOPE * v.x;
        v.y = v.y * sc[1] + bi[1]; v.y = v.y > 0.f ? v.y : NEG_SLOPE * v.y;
        v.z = v.z * sc[2] + bi[2]; v.z = v.z > 0.f ? v.z : NEG_SLOPE * v.z;
        v.w = v.w * sc[3] + bi[3]; v.w = v.w > 0.f ? v.w : NEG_SLOPE * v.w;
        ((float4*)y)[idx] = v;
    }
}

extern "C" void kernel_launch(void* const* d_in, const int* in_sizes, int n_in,
                              void* d_out, int out_size, void* d_ws, size_t ws_size,
                              hipStream_t stream)
{
    const float* feats = (const float*)d_in[0];
    const int*   nidx  = (const int*)d_in[1];
    const int*   nmask = (const int*)d_in[2];
    const float* W     = (const float*)d_in[3];
    const float* gamma = (const float*)d_in[4];
    const float* beta  = (const float*)d_in[5];

    float* y = (float*)d_out;

    // ws layout
    float*          accum  = (float*)d_ws;                               // 1 KB
    float*          sb     = (float*)((char*)d_ws + 1024);               // 1 KB
    unsigned short* Wt     = (unsigned short*)((char*)d_ws + 4096);      // 442 KB
    unsigned short* featsb = (unsigned short*)((char*)d_ws + 458752);    // 16.8 MB
    const bool use_bf16 = ws_size >= (458752 + (size_t)NPTS * CIN * 2);

    hipMemsetAsync(accum, 0, 2 * COUT * sizeof(float), stream);
    prep_w<<<(K * COUT * CIN + 255) / 256, 256, 0, stream>>>(W, Wt);
    if (use_bf16) {
        prep_f<<<(NPTS * CIN / 8) / 256, 256, 0, stream>>>(feats, featsb);
        conv_kernel<true><<<NPTS / BM, 256, 0, stream>>>(feats, featsb, nidx, nmask, Wt, y, accum);
    } else {
        conv_kernel<false><<<NPTS / BM, 256, 0, stream>>>(feats, featsb, nidx, nmask, Wt, y, accum);
    }
    finalize_kernel<<<1, 128, 0, stream>>>(accum, gamma, beta, sb);
    bn_kernel<<<2048, 256, 0, stream>>>(y, sb);
}

// Round 5
// 147.134 us; speedup vs baseline: 7.4126x; 1.1780x over previous
//
#include <hip/hip_runtime.h>
#include <hip/hip_bf16.h>

#define NPTS 131072
#define K 27
#define CIN 64
#define COUT 128
#define BM 64                 // rows per conv block

constexpr float BN_EPS = 1e-5f;
constexpr float NEG_SLOPE = 0.01f;

typedef __attribute__((ext_vector_type(8))) short short8;
typedef __attribute__((ext_vector_type(4))) float f32x4;

__device__ inline unsigned int pk_bf16(float a, float b) {
    __hip_bfloat16 ha = __float2bfloat16(a), hb = __float2bfloat16(b);
    unsigned short ua = *reinterpret_cast<unsigned short*>(&ha);
    unsigned short ub = *reinterpret_cast<unsigned short*>(&hb);
    return (unsigned int)ua | ((unsigned int)ub << 16);
}

// ---------------------------------------------------------------------------
// prep_w: W [27][64][128] f32 -> Wt [27][128][64] bf16
// ---------------------------------------------------------------------------
__global__ __launch_bounds__(256) void prep_w(
    const float* __restrict__ W, unsigned short* __restrict__ Wt)
{
    int o = blockIdx.x * 256 + threadIdx.x;           // 27*128*64 = 221184
    if (o >= K * COUT * CIN) return;
    int k  = o / (COUT * CIN);
    int r  = o % (COUT * CIN);
    int co = r / CIN;
    int ci = r % CIN;
    __hip_bfloat16 h = __float2bfloat16(W[(k * CIN + ci) * COUT + co]);
    Wt[o] = *reinterpret_cast<unsigned short*>(&h);
}

// ---------------------------------------------------------------------------
// prep_f: feats [N][64] f32 -> bf16 rows (row NPTS is the zero sentinel,
// cleared by hipMemsetAsync).
// ---------------------------------------------------------------------------
__global__ __launch_bounds__(256) void prep_f(
    const float* __restrict__ feats, unsigned short* __restrict__ featsb)
{
    size_t t = (size_t)blockIdx.x * 256 + threadIdx.x;   // 1,048,576 threads
    const float4* src = (const float4*)(feats) + t * 2;
    float4 v0 = src[0], v1 = src[1];
    uint4 o;
    o.x = pk_bf16(v0.x, v0.y); o.y = pk_bf16(v0.z, v0.w);
    o.z = pk_bf16(v1.x, v1.y); o.w = pk_bf16(v1.z, v1.w);
    ((uint4*)featsb)[t] = o;
}

// ---------------------------------------------------------------------------
// prep_idx: fold mask into index (masked-off -> sentinel zero row NPTS)
// ---------------------------------------------------------------------------
__global__ __launch_bounds__(256) void prep_idx(
    const int* __restrict__ nidx, const int* __restrict__ nmask,
    int* __restrict__ midx)
{
    int t = blockIdx.x * 256 + threadIdx.x;              // 3,538,944
    if (t < NPTS * K) midx[t] = nmask[t] ? nidx[t] : NPTS;
}

// ---------------------------------------------------------------------------
// conv: MFMA gather-conv, 256 thr = 4 waves (2x2), 64x128 tile, fused stats.
// T14 pipeline: k+1's gather/W loads are issued into REGISTERS immediately
// after k's LDS write, so global latency hides under MFMA k + both barriers.
// ---------------------------------------------------------------------------
template<bool MIDX>
__global__ __launch_bounds__(256) void conv_kernel(
    const unsigned short* __restrict__ featsb,   // NPTS+1 rows (last = zeros)
    const int* __restrict__ midx,                // if MIDX
    const int* __restrict__ nidx,                // else
    const int* __restrict__ nmask,
    const unsigned short* __restrict__ Wt,
    float* __restrict__ y,
    float* __restrict__ accum)                   // [256]: sums then sumsqs
{
    __shared__ unsigned char Alds[BM * CIN * 2];      // 8 KB
    __shared__ unsigned char Blds[COUT * CIN * 2];    // 16 KB (total 24 KB)

    const int tid  = threadIdx.x;
    const int l    = tid & 63;
    const int wid  = tid >> 6;
    const int wr   = wid >> 1;
    const int wc   = wid & 1;
    const int base = blockIdx.x * BM;

    const int arow = tid >> 2;        // 4 threads/row, 32 B each
    const int aq   = tid & 3;
    const int bcol = tid >> 1;        // 2 threads/col, 64 B each
    const int bh   = tid & 1;

    auto loadIdx = [&](int k) -> int {
        int o = (base + arow) * K + k;
        if constexpr (MIDX) return midx[o];
        else                return nmask[o] ? nidx[o] : NPTS;
    };

    f32x4 acc[2][4];
#pragma unroll
    for (int m = 0; m < 2; ++m)
#pragma unroll
        for (int n = 0; n < 4; ++n) acc[m][n] = (f32x4)0.f;

    // ---- prologue: issue k=0 loads, prefetch k=1's index ----
    int id_cur = loadIdx(0);
    const uint4* asrc = (const uint4*)(featsb + (size_t)id_cur * CIN) + aq * 2;
    uint4 a0 = asrc[0], a1 = asrc[1];
    const uint4* bsrc = (const uint4*)(Wt + (size_t)bcol * CIN) + bh * 4;
    uint4 b0 = bsrc[0], b1 = bsrc[1], b2 = bsrc[2], b3 = bsrc[3];
    int id_nxt = loadIdx(1);

    const int aswz = (arow & 7) << 4;
    unsigned char* ap = Alds + arow * 128;
    const int bswz = (bcol & 7) << 4;
    unsigned char* bp = Blds + bcol * 128;

    for (int k = 0; k < K; ++k) {
        __syncthreads();              // all waves done reading LDS tile k-1
        // ---- write staged regs -> swizzled LDS ----
        *(uint4*)(ap + ((aq * 32 +  0) ^ aswz)) = a0;
        *(uint4*)(ap + ((aq * 32 + 16) ^ aswz)) = a1;
        *(uint4*)(bp + ((bh * 64 +  0) ^ bswz)) = b0;
        *(uint4*)(bp + ((bh * 64 + 16) ^ bswz)) = b1;
        *(uint4*)(bp + ((bh * 64 + 32) ^ bswz)) = b2;
        *(uint4*)(bp + ((bh * 64 + 48) ^ bswz)) = b3;
        // ---- issue k+1 loads (fly during MFMA k) ----
        if (k + 1 < K) {
            const uint4* an = (const uint4*)(featsb + (size_t)id_nxt * CIN) + aq * 2;
            a0 = an[0]; a1 = an[1];
            const uint4* bn = (const uint4*)(Wt + ((size_t)(k + 1) * COUT + bcol) * CIN) + bh * 4;
            b0 = bn[0]; b1 = bn[1]; b2 = bn[2]; b3 = bn[3];
            id_nxt = loadIdx(k + 2 < K ? k + 2 : K - 1);
        }
        __syncthreads();              // LDS tile k visible

        // ---- 2 MFMA K-steps of 32 ----
#pragma unroll
        for (int ks = 0; ks < 2; ++ks) {
            const int kbyte = ks * 64 + (l >> 4) * 16;
            short8 a[2], b[4];
#pragma unroll
            for (int m = 0; m < 2; ++m) {
                int row = wr * 32 + m * 16 + (l & 15);
                a[m] = *(const short8*)(Alds + row * 128 + (kbyte ^ ((row & 7) << 4)));
            }
#pragma unroll
            for (int n = 0; n < 4; ++n) {
                int col = wc * 64 + n * 16 + (l & 15);
                b[n] = *(const short8*)(Blds + col * 128 + (kbyte ^ ((col & 7) << 4)));
            }
#pragma unroll
            for (int m = 0; m < 2; ++m)
#pragma unroll
                for (int n = 0; n < 4; ++n)
                    acc[m][n] = __builtin_amdgcn_mfma_f32_16x16x32_bf16(
                        a[m], b[n], acc[m][n], 0, 0, 0);
        }
    }

    // ---- y write: C/D layout col=l&15, row=(l>>4)*4+r ----
#pragma unroll
    for (int m = 0; m < 2; ++m)
#pragma unroll
        for (int n = 0; n < 4; ++n) {
            int gcol = wc * 64 + n * 16 + (l & 15);
#pragma unroll
            for (int r = 0; r < 4; ++r) {
                int grow = base + wr * 32 + m * 16 + (l >> 4) * 4 + r;
                y[(size_t)grow * COUT + gcol] = acc[m][n][r];
            }
        }

    // ---- fused per-block BN stats (reuse Alds as the combine buffer) ----
    float sv[4], s2v[4];
#pragma unroll
    for (int n = 0; n < 4; ++n) {
        float s = 0.f, s2 = 0.f;
#pragma unroll
        for (int m = 0; m < 2; ++m)
#pragma unroll
            for (int r = 0; r < 4; ++r) { float v = acc[m][n][r]; s += v; s2 += v * v; }
        s  += __shfl_xor(s, 16);  s  += __shfl_xor(s, 32);
        s2 += __shfl_xor(s2, 16); s2 += __shfl_xor(s2, 32);
        sv[n] = s; s2v[n] = s2;
    }
    __syncthreads();                  // everyone done reading Alds/Blds
    float* statf = (float*)Alds;      // [2][2][128] = 4 KB
    if (l < 16) {
#pragma unroll
        for (int n = 0; n < 4; ++n) {
            int c = wc * 64 + n * 16 + l;
            statf[(0 * 2 + wr) * 128 + c] = sv[n];
            statf[(1 * 2 + wr) * 128 + c] = s2v[n];
        }
    }
    __syncthreads();
    if (tid < 128) {
        atomicAdd(&accum[tid],       statf[0 * 128 + tid] + statf[1 * 128 + tid]);
        atomicAdd(&accum[128 + tid], statf[2 * 128 + tid] + statf[3 * 128 + tid]);
    }
}

// ---------------------------------------------------------------------------
// finalize: fold mean/var/gamma/beta into per-channel scale+bias
// ---------------------------------------------------------------------------
__global__ void finalize_kernel(const float* __restrict__ accum,
                                const float* __restrict__ gamma,
                                const float* __restrict__ beta,
                                float* __restrict__ sb)
{
    int c = threadIdx.x;                      // 128 threads
    float invN  = 1.0f / (float)NPTS;
    float mean  = accum[c] * invN;
    float var   = accum[128 + c] * invN - mean * mean;
    float scale = gamma[c] * rsqrtf(var + BN_EPS);
    sb[c]       = scale;
    sb[128 + c] = beta[c] - mean * scale;
}

// ---------------------------------------------------------------------------
// bn: y = leaky(y*scale+bias), float4-vectorized, scale/bias in registers
// ---------------------------------------------------------------------------
__global__ __launch_bounds__(256) void bn_kernel(
    float* __restrict__ y, const float* __restrict__ sb)
{
    size_t start = (size_t)blockIdx.x * blockDim.x + threadIdx.x;
    int c0 = (int)((start * 4) & (COUT - 1));   // invariant under grid stride
    float sc[4], bi[4];
#pragma unroll
    for (int j = 0; j < 4; ++j) { sc[j] = sb[c0 + j]; bi[j] = sb[COUT + c0 + j]; }

    const size_t total = (size_t)NPTS * COUT / 4;
    const size_t step  = (size_t)gridDim.x * blockDim.x;
    for (size_t idx = start; idx < total; idx += step) {
        float4 v = ((const float4*)y)[idx];
        v.x = v.x * sc[0] + bi[0]; v.x = v.x > 0.f ? v.x : NEG_SLOPE * v.x;
        v.y = v.y * sc[1] + bi[1]; v.y = v.y > 0.f ? v.y : NEG_SLOPE * v.y;
        v.z = v.z * sc[2] + bi[2]; v.z = v.z > 0.f ? v.z : NEG_SLOPE * v.z;
        v.w = v.w * sc[3] + bi[3]; v.w = v.w > 0.f ? v.w : NEG_SLOPE * v.w;
        ((float4*)y)[idx] = v;
    }
}

extern "C" void kernel_launch(void* const* d_in, const int* in_sizes, int n_in,
                              void* d_out, int out_size, void* d_ws, size_t ws_size,
                              hipStream_t stream)
{
    const float* feats = (const float*)d_in[0];
    const int*   nidx  = (const int*)d_in[1];
    const int*   nmask = (const int*)d_in[2];
    const float* W     = (const float*)d_in[3];
    const float* gamma = (const float*)d_in[4];
    const float* beta  = (const float*)d_in[5];

    float* y = (float*)d_out;

    // ws layout
    float*          accum  = (float*)d_ws;                               // 1 KB
    float*          sb     = (float*)((char*)d_ws + 1024);               // 1 KB
    unsigned short* Wt     = (unsigned short*)((char*)d_ws + 4096);      // 442 KB
    unsigned short* featsb = (unsigned short*)((char*)d_ws + 458752);    // 16.78 MB (NPTS+1 rows)
    int*            midx   = (int*)((char*)d_ws + 17236224);             // 14.16 MB
    const size_t need_midx = 17236224 + (size_t)NPTS * K * sizeof(int);
    const bool use_midx = ws_size >= need_midx;

    hipMemsetAsync(accum, 0, 2 * COUT * sizeof(float), stream);
    hipMemsetAsync(featsb + (size_t)NPTS * CIN, 0, CIN * 2, stream);   // zero sentinel row

    prep_w<<<(K * COUT * CIN + 255) / 256, 256, 0, stream>>>(W, Wt);
    prep_f<<<(NPTS * CIN / 8) / 256, 256, 0, stream>>>(feats, featsb);
    if (use_midx) {
        prep_idx<<<(NPTS * K + 255) / 256, 256, 0, stream>>>(nidx, nmask, midx);
        conv_kernel<true><<<NPTS / BM, 256, 0, stream>>>(featsb, midx, nidx, nmask, Wt, y, accum);
    } else {
        conv_kernel<false><<<NPTS / BM, 256, 0, stream>>>(featsb, midx, nidx, nmask, Wt, y, accum);
    }
    finalize_kernel<<<1, 128, 0, stream>>>(accum, gamma, beta, sb);
    bn_kernel<<<2048, 256, 0, stream>>>(y, sb);
}